// Round 19
// baseline (220.583 us; speedup 1.0000x reference)
//
#include <hip/hip_runtime.h>
#include <hip/hip_bf16.h>
#include <stdint.h>

#define B_  4
#define N_  2048
#define C_  1024
#define H_  16
#define HD_ 64
#define M_  (B_*N_)     // 8192
#define K3_ (3*C_)      // 3072

typedef __bf16 bf16;
typedef __bf16 bf16x8 __attribute__((ext_vector_type(8)));
typedef __bf16 bf16x4 __attribute__((ext_vector_type(4)));
typedef float f32x4 __attribute__((ext_vector_type(4)));
typedef float f32x16 __attribute__((ext_vector_type(16)));

#if __has_builtin(__builtin_amdgcn_exp2f)
#define EXP2(x) __builtin_amdgcn_exp2f(x)
#else
#define EXP2(x) exp2f(x)
#endif

// ---------------- fused f32 -> bf16 cast for 3 arrays ----------------
__global__ void castk3(const float* __restrict__ a, bf16* __restrict__ oa, int na4,
                       const float* __restrict__ b, bf16* __restrict__ ob, int nb4,
                       const float* __restrict__ c, bf16* __restrict__ oc, int nc4) {
    int total = na4 + nb4 + nc4;
    int stride = gridDim.x * blockDim.x;
    for (int i = blockIdx.x * blockDim.x + threadIdx.x; i < total; i += stride) {
        const float* src; bf16* dst; int j = i;
        if (j < na4)              { src = a; dst = oa; }
        else if ((j -= na4) < nb4){ src = b; dst = ob; }
        else                      { j -= nb4; src = c; dst = oc; }
        float4 v = reinterpret_cast<const float4*>(src)[j];
        bf16x4 o;
        o[0] = (bf16)v.x; o[1] = (bf16)v.y; o[2] = (bf16)v.z; o[3] = (bf16)v.w;
        *reinterpret_cast<bf16x4*>(dst + (size_t)j * 4) = o;
    }
}

__device__ __forceinline__ void gll16(const bf16* g, const bf16* l) {
    __builtin_amdgcn_global_load_lds(
        (const __attribute__((address_space(1))) void*)g,
        (__attribute__((address_space(3))) void*)l, 16, 0, 0);
}

__device__ __forceinline__ uint32_t pkbf(float a, float b) {
    union { bf16 h[2]; uint32_t u; } U;
    U.h[0] = (bf16)a; U.h[1] = (bf16)b;
    return U.u;
}

__device__ __forceinline__ uint32_t pkraw(bf16 a, bf16 b) {
    union { bf16 h[2]; uint32_t u; } U;
    U.h[0] = a; U.h[1] = b;
    return U.u;
}

// ---------------- GEMM  out[m][n] = sum_k A[m][k] * B[n][k] ----------------
// BK=64, XOR-swizzled LDS (attn-proven pattern: LDS[r][cc] holds global
// chunk cc^(r&7); staged via pre-swizzled global source, gll16 dest linear).
// 128B rows -> ds_read_b128 banks = cc*4: 8 banks x 2 lanes = 2-way = free
// (was 8-way at 64B rows). Half the iterations -> half the barrier drains.
// MODE 0 epilogue: RoPE on q,k (scale folds 1/sqrt(HD)*log2e); MODE 1: +bias f32.
template<int MODE>
__global__ __launch_bounds__(256, 2)
void gemm_bt(const bf16* __restrict__ A, const bf16* __restrict__ Bm,
             int Nn, int Kk,
             bf16* __restrict__ qout, bf16* __restrict__ kout, bf16* __restrict__ vout,
             const float* __restrict__ fcos, const float* __restrict__ fsin,
             const float* __restrict__ bias, float* __restrict__ Cout)
{
    __shared__ bf16 a_lds[2][128 * 64];
    __shared__ bf16 b_lds[2][128 * 64];
    const int tid  = threadIdx.x;
    const int lane = tid & 63;
    const int w    = tid >> 6;
    const int wr   = w >> 1, wc = w & 1;
    const int ntile = Nn >> 7;
    // bijective XCD swizzle (gridDim.x % 8 == 0 for both launches)
    const int nwg = gridDim.x, cpx = nwg >> 3;
    const int swz = (blockIdx.x & 7) * cpx + (blockIdx.x >> 3);
    const int bx = swz % ntile, by = swz / ntile;
    const int m0 = by * 128, n0 = bx * 128;

    f32x4 acc[4][4] = {};

    // staging: thread stages 4 chunks per array per K-tile.
    // chunk ci = tid + 256*j -> row = tid>>3 + 32*j, col-chunk = tid&7 (fixed).
    // pre-swizzled source col = ((tid&7) ^ (row&7))*8; row&7 invariant in j.
    const int srow = tid >> 3;
    const int scol = ((tid & 7) ^ (srow & 7)) * 8;
    const bf16* gaS = A  + (size_t)(m0 + srow) * Kk + scol;
    const bf16* gbS = Bm + (size_t)(n0 + srow) * Kk + scol;
    const size_t rj = (size_t)32 * Kk;   // +32 rows per load j

#define STAGE_G(slot, koff) do {                                               \
        _Pragma("unroll")                                                      \
        for (int j = 0; j < 4; ++j) {                                          \
            gll16(gaS + (koff) + j * rj, &a_lds[slot][w * 512 + j * 2048]);    \
            gll16(gbS + (koff) + j * rj, &b_lds[slot][w * 512 + j * 2048]);    \
        }                                                                      \
    } while (0)

    const int rA = lane & 15, hi = lane >> 4;
    const int x7 = rA & 7;

    // ---- prologue: stage K-tile 0 into slot 0 ----
    STAGE_G(0, 0);
    __syncthreads();

    for (int k0 = 0; k0 < Kk; k0 += 64) {
        const int cur = (k0 >> 6) & 1, nxt = cur ^ 1;
        if (k0 + 64 < Kk) STAGE_G(nxt, k0 + 64);

        const char* aB = reinterpret_cast<const char*>(&a_lds[cur][0]);
        const char* bB = reinterpret_cast<const char*>(&b_lds[cur][0]);
#pragma unroll
        for (int ks = 0; ks < 2; ++ks) {
            const int cc = ((ks * 4 + hi) ^ x7) * 16;
            bf16x8 af[4], bfr[4];
#pragma unroll
            for (int m = 0; m < 4; ++m)
                af[m] = *reinterpret_cast<const bf16x8*>(aB + (wr * 64 + m * 16 + rA) * 128 + cc);
#pragma unroll
            for (int n = 0; n < 4; ++n)
                bfr[n] = *reinterpret_cast<const bf16x8*>(bB + (wc * 64 + n * 16 + rA) * 128 + cc);
#pragma unroll
            for (int m = 0; m < 4; ++m)
#pragma unroll
                for (int n = 0; n < 4; ++n)
                    acc[m][n] = __builtin_amdgcn_mfma_f32_16x16x32_bf16(af[m], bfr[n], acc[m][n], 0, 0, 0);
        }
        __syncthreads();   // drains prefetch (vmcnt) + guards slot reuse
    }
#undef STAGE_G

    if (MODE == 1) {
#pragma unroll
        for (int n = 0; n < 4; ++n) {
            int cg = n0 + wc * 64 + n * 16 + (lane & 15);
            float bv = bias[cg];
#pragma unroll
            for (int m = 0; m < 4; ++m) {
                int rg = m0 + wr * 64 + m * 16 + (lane >> 4) * 4;
#pragma unroll
                for (int r = 0; r < 4; ++r)
                    Cout[(size_t)(rg + r) * Nn + cg] = acc[m][n][r] + bv;
            }
        }
    } else {
        const int part = n0 >> 10;
#pragma unroll
        for (int n = 0; n < 4; ++n) {
            int cg  = n0 + wc * 64 + n * 16 + (lane & 15);
            int rem = cg & 1023;
            int h   = rem >> 6, hd = rem & 63;
#pragma unroll
            for (int m = 0; m < 4; ++m) {
#pragma unroll
                for (int r = 0; r < 4; ++r) {
                    int rg   = m0 + wr * 64 + m * 16 + (lane >> 4) * 4 + r;
                    int b    = rg >> 11, nrow = rg & 2047;
                    float val = acc[m][n][r];
                    size_t oi = ((size_t)(b * 16 + h) * N_ + nrow) * HD_ + hd;
                    if (part == 2) {
                        vout[oi] = (bf16)val;
                    } else {
                        float p   = __shfl_xor(val, 1);
                        float cth = fcos[nrow * 32 + (hd >> 1)];
                        float sth = fsin[nrow * 32 + (hd >> 1)];
                        float o   = (lane & 1) ? (val * cth + p * sth) : (val * cth - p * sth);
                        if (part == 0) { o *= 0.18033688011112042f; qout[oi] = (bf16)o; } // 0.125*log2(e)
                        else           { kout[oi] = (bf16)o; }
                    }
                }
            }
        }
    }
}

// ---------------- flash attention (round-18 verified: dual 32-q streams) ----
#define NT_ (N_ / 64)
__global__ __launch_bounds__(256, 2)
void attn_kernel(const bf16* __restrict__ Q, const bf16* __restrict__ Kb,
                 const bf16* __restrict__ Vb, bf16* __restrict__ Ob)
{
    __shared__ bf16 k_lds[2][64 * 64];
    __shared__ bf16 vt_lds[2][64 * 64];
    const int tid = threadIdx.x, lane = tid & 63, w = tid >> 6;
    const int h5  = lane >> 5;
    const int l31 = lane & 31;
    const int nqt = N_ / 256;            // 8 (256 q-rows per block)
    const int cpx = gridDim.x >> 3;      // 64
    const int swzb = (blockIdx.x & 7) * cpx + (blockIdx.x >> 3);
    const int bh = swzb / nqt, qt = swzb % nqt;
    const size_t base = (size_t)bh * N_ * HD_;
    const int q0 = qt * 256 + w * 64;    // wave owns q0 .. q0+63 (2 halves of 32)

    bf16x8 qf[2][4];
#pragma unroll
    for (int h = 0; h < 2; ++h) {
        const bf16* qp = Q + base + (size_t)(q0 + h * 32 + l31) * HD_ + h5 * 8;
#pragma unroll
        for (int t = 0; t < 4; ++t)
            qf[h][t] = *reinterpret_cast<const bf16x8*>(qp + t * 16);
    }

    f32x16 oT[2][2] = {};
    float l0 = 0.f, l1 = 0.f;

    const int kRowA = tid >> 3;
    const int kColA = ((tid & 7) ^ (kRowA & 7)) * 8;
    const int kRowB = kRowA + 32;
    const int kColB = ((tid & 7) ^ (kRowB & 7)) * 8;
    const bf16* kSrcA = Kb + base + (size_t)kRowA * HD_ + kColA;
    const bf16* kSrcB = Kb + base + (size_t)kRowB * HD_ + kColB;

    const int kp = tid & 31, dc = tid >> 5;
    const bf16* vSrc0 = Vb + base + (size_t)(2 * kp) * HD_ + dc * 8;
    const bf16* vSrc1 = vSrc0 + HD_;

#define STORE_VT(bufidx, va, vb) do {                                              \
        char* vtb = reinterpret_cast<char*>(&vt_lds[0][0]) + (bufidx) * 8192;      \
        _Pragma("unroll")                                                          \
        for (int j = 0; j < 8; ++j) {                                              \
            int byteoff = (dc * 8 + j) * 128 + ((4 * kp) ^ (j << 4));              \
            *reinterpret_cast<uint32_t*>(vtb + byteoff) = pkraw((va)[j], (vb)[j]); \
        }                                                                          \
    } while (0)

    bf16x8 v0 = *reinterpret_cast<const bf16x8*>(vSrc0);
    bf16x8 v1 = *reinterpret_cast<const bf16x8*>(vSrc1);
    gll16(kSrcA, &k_lds[0][w * 512]);
    gll16(kSrcB, &k_lds[0][2048 + w * 512]);
    STORE_VT(0, v0, v1);
    __syncthreads();

    for (int it = 0; it < NT_; ++it) {
        const int cur = it & 1, nxt = cur ^ 1;
        const bool more = (it + 1 < NT_);

        if (more) {
            size_t adv = (size_t)(it + 1) * 64 * HD_;
            v0 = *reinterpret_cast<const bf16x8*>(vSrc0 + adv);
            v1 = *reinterpret_cast<const bf16x8*>(vSrc1 + adv);
            gll16(kSrcA + adv, &k_lds[nxt][w * 512]);
            gll16(kSrcB + adv, &k_lds[nxt][2048 + w * 512]);
        }

        const char* kbase  = reinterpret_cast<const char*>(&k_lds[0][0]) + cur * 8192;
        const char* vtbase = reinterpret_cast<const char*>(&vt_lds[0][0]) + cur * 8192;
        float psum0 = 0.f, psum1 = 0.f;

#pragma unroll
        for (int s = 0; s < 2; ++s) {
            f32x16 st0 = {}, st1 = {};
            const int row = s * 32 + l31;
#pragma unroll
            for (int t = 0; t < 4; ++t) {
                int cc = (2 * t + h5) ^ (row & 7);
                bf16x8 kf = *reinterpret_cast<const bf16x8*>(kbase + row * 128 + cc * 16);
                st0 = __builtin_amdgcn_mfma_f32_32x32x16_bf16(kf, qf[0][t], st0, 0, 0, 0);
                st1 = __builtin_amdgcn_mfma_f32_32x32x16_bf16(kf, qf[1][t], st1, 0, 0, 0);
            }

#pragma unroll
            for (int i = 0; i < 16; ++i) st0[i] = EXP2(st0[i]);
#pragma unroll
            for (int i = 0; i < 16; ++i) st1[i] = EXP2(st1[i]);

            float t8[8], u8[8];
#pragma unroll
            for (int i = 0; i < 8; ++i) { t8[i] = st0[i] + st0[i + 8]; u8[i] = st1[i] + st1[i + 8]; }
#pragma unroll
            for (int i = 0; i < 4; ++i) { t8[i] = t8[i] + t8[i + 4];   u8[i] = u8[i] + u8[i + 4]; }
            psum0 += (t8[0] + t8[1]) + (t8[2] + t8[3]);
            psum1 += (u8[0] + u8[1]) + (u8[2] + u8[3]);

            uint32_t pk0[4][2], pk1[4][2];
#pragma unroll
            for (int g = 0; g < 4; ++g) {
                pk0[g][0] = pkbf(st0[4 * g + 0], st0[4 * g + 1]);
                pk0[g][1] = pkbf(st0[4 * g + 2], st0[4 * g + 3]);
                pk1[g][0] = pkbf(st1[4 * g + 0], st1[4 * g + 1]);
                pk1[g][1] = pkbf(st1[4 * g + 2], st1[4 * g + 3]);
            }
#pragma unroll
            for (int tt = 0; tt < 2; ++tt) {
                const int t = 2 * s + tt;
                uint32_t a0 = pk0[2 * tt][0], b0 = pk0[2 * tt + 1][0];
                uint32_t a1 = pk0[2 * tt][1], b1 = pk0[2 * tt + 1][1];
                uint32_t c0 = pk1[2 * tt][0], d0 = pk1[2 * tt + 1][0];
                uint32_t c1 = pk1[2 * tt][1], d1 = pk1[2 * tt + 1][1];
                asm volatile("v_permlane32_swap_b32 %0, %1" : "+v"(a0), "+v"(b0));
                asm volatile("v_permlane32_swap_b32 %0, %1" : "+v"(a1), "+v"(b1));
                asm volatile("v_permlane32_swap_b32 %0, %1" : "+v"(c0), "+v"(d0));
                asm volatile("v_permlane32_swap_b32 %0, %1" : "+v"(c1), "+v"(d1));
                union { uint32_t u[4]; bf16x8 v; } U0, U1;
                U0.u[0] = a0; U0.u[1] = a1; U0.u[2] = b0; U0.u[3] = b1;
                U1.u[0] = c0; U1.u[1] = c1; U1.u[2] = d0; U1.u[3] = d1;
#pragma unroll
                for (int n = 0; n < 2; ++n) {
                    int vrow = n * 32 + l31;
                    int cc   = (2 * t + h5) ^ (vrow & 7);
                    bf16x8 vf = *reinterpret_cast<const bf16x8*>(vtbase + vrow * 128 + cc * 16);
                    oT[0][n] = __builtin_amdgcn_mfma_f32_32x32x16_bf16(vf, U0.v, oT[0][n], 0, 0, 0);
                    oT[1][n] = __builtin_amdgcn_mfma_f32_32x32x16_bf16(vf, U1.v, oT[1][n], 0, 0, 0);
                }
            }

            if (s == 0 && more) STORE_VT(nxt, v0, v1);
        }

        psum0 += __shfl_xor(psum0, 32);
        psum1 += __shfl_xor(psum1, 32);
        l0 += psum0;
        l1 += psum1;

        __syncthreads();
    }

    const int b = bh >> 4, hh = bh & 15;
#pragma unroll
    for (int h = 0; h < 2; ++h) {
        float inv = 1.0f / (h ? l1 : l0);
        int q = q0 + h * 32 + l31;
#pragma unroll
        for (int n = 0; n < 2; ++n)
#pragma unroll
            for (int g = 0; g < 4; ++g) {
                int d = n * 32 + 8 * g + 4 * h5;
                bf16x4 o4;
#pragma unroll
                for (int r = 0; r < 4; ++r) o4[r] = (bf16)(oT[h][n][4 * g + r] * inv);
                *reinterpret_cast<bf16x4*>(Ob + ((size_t)(b * N_ + q)) * C_ + hh * 64 + d) = o4;
            }
    }
#undef STORE_VT
}

extern "C" void kernel_launch(void* const* d_in, const int* in_sizes, int n_in,
                              void* d_out, int out_size, void* d_ws, size_t ws_size,
                              hipStream_t stream) {
    const float* x     = (const float*)d_in[0];
    const float* wqkv  = (const float*)d_in[1];
    const float* wproj = (const float*)d_in[2];
    const float* bproj = (const float*)d_in[3];
    const float* fcos  = (const float*)d_in[4];
    const float* fsin  = (const float*)d_in[5];
    float* out = (float*)d_out;

    bf16* x_bf     = (bf16*)d_ws;
    bf16* wqkv_bf  = x_bf    + (size_t)M_ * C_;
    bf16* wproj_bf = wqkv_bf + (size_t)K3_ * C_;
    bf16* qbuf     = wproj_bf + (size_t)C_ * C_;
    bf16* kbuf     = qbuf  + (size_t)M_ * C_;
    bf16* vbuf     = kbuf  + (size_t)M_ * C_;
    bf16* abuf     = vbuf  + (size_t)M_ * C_;

    castk3<<<2048, 256, 0, stream>>>(x,     x_bf,     M_ * C_ / 4,
                                     wqkv,  wqkv_bf,  K3_ * C_ / 4,
                                     wproj, wproj_bf, C_ * C_ / 4);

    gemm_bt<0><<<64 * 24, 256, 0, stream>>>(x_bf, wqkv_bf, K3_, C_,
                                            qbuf, kbuf, vbuf, fcos, fsin, nullptr, nullptr);
    attn_kernel<<<64 * 8, 256, 0, stream>>>(qbuf, kbuf, vbuf, abuf);
    gemm_bt<1><<<64 * 8, 256, 0, stream>>>(abuf, wproj_bf, C_, C_,
                                           nullptr, nullptr, nullptr, nullptr, nullptr, bproj, out);
}

// Round 20
// 200.576 us; speedup vs baseline: 1.0998x; 1.0998x over previous
//
#include <hip/hip_runtime.h>
#include <hip/hip_bf16.h>
#include <stdint.h>

#define B_  4
#define N_  2048
#define C_  1024
#define H_  16
#define HD_ 64
#define M_  (B_*N_)     // 8192
#define K3_ (3*C_)      // 3072

typedef __bf16 bf16;
typedef __bf16 bf16x8 __attribute__((ext_vector_type(8)));
typedef __bf16 bf16x4 __attribute__((ext_vector_type(4)));
typedef float f32x4 __attribute__((ext_vector_type(4)));
typedef float f32x16 __attribute__((ext_vector_type(16)));

#if __has_builtin(__builtin_amdgcn_exp2f)
#define EXP2(x) __builtin_amdgcn_exp2f(x)
#else
#define EXP2(x) exp2f(x)
#endif

// ---------------- fused f32 -> bf16 cast for 3 arrays ----------------
__global__ void castk3(const float* __restrict__ a, bf16* __restrict__ oa, int na4,
                       const float* __restrict__ b, bf16* __restrict__ ob, int nb4,
                       const float* __restrict__ c, bf16* __restrict__ oc, int nc4) {
    int total = na4 + nb4 + nc4;
    int stride = gridDim.x * blockDim.x;
    for (int i = blockIdx.x * blockDim.x + threadIdx.x; i < total; i += stride) {
        const float* src; bf16* dst; int j = i;
        if (j < na4)              { src = a; dst = oa; }
        else if ((j -= na4) < nb4){ src = b; dst = ob; }
        else                      { j -= nb4; src = c; dst = oc; }
        float4 v = reinterpret_cast<const float4*>(src)[j];
        bf16x4 o;
        o[0] = (bf16)v.x; o[1] = (bf16)v.y; o[2] = (bf16)v.z; o[3] = (bf16)v.w;
        *reinterpret_cast<bf16x4*>(dst + (size_t)j * 4) = o;
    }
}

__device__ __forceinline__ void gll16(const bf16* g, const bf16* l) {
    __builtin_amdgcn_global_load_lds(
        (const __attribute__((address_space(1))) void*)g,
        (__attribute__((address_space(3))) void*)l, 16, 0, 0);
}

__device__ __forceinline__ uint32_t pkbf(float a, float b) {
    union { bf16 h[2]; uint32_t u; } U;
    U.h[0] = (bf16)a; U.h[1] = (bf16)b;
    return U.u;
}

__device__ __forceinline__ uint32_t pkraw(bf16 a, bf16 b) {
    union { bf16 h[2]; uint32_t u; } U;
    U.h[0] = a; U.h[1] = b;
    return U.u;
}

// ---------------- GEMM  out[m][n] = sum_k A[m][k] * B[n][k] ----------------
// BK=64, XOR-swizzled LDS (LDS[r][cc] holds global chunk cc^(r&7); staged via
// pre-swizzled global source, gll16 dest linear) -> ds_read_b128 conflict-free
// (verified: SQ_LDS_BANK_CONFLICT = 0 in round 19).
// This round: SINGLE-buffered (32KB LDS) at (256,4) -> 4 blocks/CU. Round-19's
// 64KB dbuf halved occupancy and raised refetch; m114: TLP at 4 blocks/CU
// covers the drain, so the second buffer is not needed.
// MODE 0 epilogue: RoPE on q,k (scale folds 1/sqrt(HD)*log2e); MODE 1: +bias f32.
template<int MODE>
__global__ __launch_bounds__(256, 4)
void gemm_bt(const bf16* __restrict__ A, const bf16* __restrict__ Bm,
             int Nn, int Kk,
             bf16* __restrict__ qout, bf16* __restrict__ kout, bf16* __restrict__ vout,
             const float* __restrict__ fcos, const float* __restrict__ fsin,
             const float* __restrict__ bias, float* __restrict__ Cout)
{
    __shared__ bf16 a_lds[128 * 64];
    __shared__ bf16 b_lds[128 * 64];
    const int tid  = threadIdx.x;
    const int lane = tid & 63;
    const int w    = tid >> 6;
    const int wr   = w >> 1, wc = w & 1;
    const int ntile = Nn >> 7;
    // bijective XCD swizzle (gridDim.x % 8 == 0 for both launches)
    const int nwg = gridDim.x, cpx = nwg >> 3;
    const int swz = (blockIdx.x & 7) * cpx + (blockIdx.x >> 3);
    const int bx = swz % ntile, by = swz / ntile;
    const int m0 = by * 128, n0 = bx * 128;

    f32x4 acc[4][4] = {};

    // staging: thread stages 4 chunks per array per K-tile.
    // chunk ci = tid + 256*j -> row = tid>>3 + 32*j, col-chunk = tid&7 (fixed).
    // pre-swizzled source col = ((tid&7) ^ (row&7))*8; row&7 invariant in j.
    const int srow = tid >> 3;
    const int scol = ((tid & 7) ^ (srow & 7)) * 8;
    const bf16* gaS = A  + (size_t)(m0 + srow) * Kk + scol;
    const bf16* gbS = Bm + (size_t)(n0 + srow) * Kk + scol;
    const size_t rj = (size_t)32 * Kk;   // +32 rows per load j

#define STAGE_G(koff) do {                                                     \
        _Pragma("unroll")                                                      \
        for (int j = 0; j < 4; ++j) {                                          \
            gll16(gaS + (koff) + j * rj, &a_lds[w * 512 + j * 2048]);          \
            gll16(gbS + (koff) + j * rj, &b_lds[w * 512 + j * 2048]);          \
        }                                                                      \
    } while (0)

    const int rA = lane & 15, hi = lane >> 4;
    const int x7 = rA & 7;

    for (int k0 = 0; k0 < Kk; k0 += 64) {
        STAGE_G(k0);
        __syncthreads();   // drain vmcnt(0): tile ready

        const char* aB = reinterpret_cast<const char*>(&a_lds[0]);
        const char* bB = reinterpret_cast<const char*>(&b_lds[0]);
#pragma unroll
        for (int ks = 0; ks < 2; ++ks) {
            const int cc = ((ks * 4 + hi) ^ x7) * 16;
            bf16x8 af[4], bfr[4];
#pragma unroll
            for (int m = 0; m < 4; ++m)
                af[m] = *reinterpret_cast<const bf16x8*>(aB + (wr * 64 + m * 16 + rA) * 128 + cc);
#pragma unroll
            for (int n = 0; n < 4; ++n)
                bfr[n] = *reinterpret_cast<const bf16x8*>(bB + (wc * 64 + n * 16 + rA) * 128 + cc);
#pragma unroll
            for (int m = 0; m < 4; ++m)
#pragma unroll
                for (int n = 0; n < 4; ++n)
                    acc[m][n] = __builtin_amdgcn_mfma_f32_16x16x32_bf16(af[m], bfr[n], acc[m][n], 0, 0, 0);
        }
        __syncthreads();   // WAR guard before next stage
    }
#undef STAGE_G

    if (MODE == 1) {
#pragma unroll
        for (int n = 0; n < 4; ++n) {
            int cg = n0 + wc * 64 + n * 16 + (lane & 15);
            float bv = bias[cg];
#pragma unroll
            for (int m = 0; m < 4; ++m) {
                int rg = m0 + wr * 64 + m * 16 + (lane >> 4) * 4;
#pragma unroll
                for (int r = 0; r < 4; ++r)
                    Cout[(size_t)(rg + r) * Nn + cg] = acc[m][n][r] + bv;
            }
        }
    } else {
        const int part = n0 >> 10;
#pragma unroll
        for (int n = 0; n < 4; ++n) {
            int cg  = n0 + wc * 64 + n * 16 + (lane & 15);
            int rem = cg & 1023;
            int h   = rem >> 6, hd = rem & 63;
#pragma unroll
            for (int m = 0; m < 4; ++m) {
#pragma unroll
                for (int r = 0; r < 4; ++r) {
                    int rg   = m0 + wr * 64 + m * 16 + (lane >> 4) * 4 + r;
                    int b    = rg >> 11, nrow = rg & 2047;
                    float val = acc[m][n][r];
                    size_t oi = ((size_t)(b * 16 + h) * N_ + nrow) * HD_ + hd;
                    if (part == 2) {
                        vout[oi] = (bf16)val;
                    } else {
                        float p   = __shfl_xor(val, 1);
                        float cth = fcos[nrow * 32 + (hd >> 1)];
                        float sth = fsin[nrow * 32 + (hd >> 1)];
                        float o   = (lane & 1) ? (val * cth + p * sth) : (val * cth - p * sth);
                        if (part == 0) { o *= 0.18033688011112042f; qout[oi] = (bf16)o; } // 0.125*log2(e)
                        else           { kout[oi] = (bf16)o; }
                    }
                }
            }
        }
    }
}

// ---------------- flash attention (round-18 verified: dual 32-q streams) ----
#define NT_ (N_ / 64)
__global__ __launch_bounds__(256, 2)
void attn_kernel(const bf16* __restrict__ Q, const bf16* __restrict__ Kb,
                 const bf16* __restrict__ Vb, bf16* __restrict__ Ob)
{
    __shared__ bf16 k_lds[2][64 * 64];
    __shared__ bf16 vt_lds[2][64 * 64];
    const int tid = threadIdx.x, lane = tid & 63, w = tid >> 6;
    const int h5  = lane >> 5;
    const int l31 = lane & 31;
    const int nqt = N_ / 256;            // 8 (256 q-rows per block)
    const int cpx = gridDim.x >> 3;      // 64
    const int swzb = (blockIdx.x & 7) * cpx + (blockIdx.x >> 3);
    const int bh = swzb / nqt, qt = swzb % nqt;
    const size_t base = (size_t)bh * N_ * HD_;
    const int q0 = qt * 256 + w * 64;    // wave owns q0 .. q0+63 (2 halves of 32)

    bf16x8 qf[2][4];
#pragma unroll
    for (int h = 0; h < 2; ++h) {
        const bf16* qp = Q + base + (size_t)(q0 + h * 32 + l31) * HD_ + h5 * 8;
#pragma unroll
        for (int t = 0; t < 4; ++t)
            qf[h][t] = *reinterpret_cast<const bf16x8*>(qp + t * 16);
    }

    f32x16 oT[2][2] = {};
    float l0 = 0.f, l1 = 0.f;

    const int kRowA = tid >> 3;
    const int kColA = ((tid & 7) ^ (kRowA & 7)) * 8;
    const int kRowB = kRowA + 32;
    const int kColB = ((tid & 7) ^ (kRowB & 7)) * 8;
    const bf16* kSrcA = Kb + base + (size_t)kRowA * HD_ + kColA;
    const bf16* kSrcB = Kb + base + (size_t)kRowB * HD_ + kColB;

    const int kp = tid & 31, dc = tid >> 5;
    const bf16* vSrc0 = Vb + base + (size_t)(2 * kp) * HD_ + dc * 8;
    const bf16* vSrc1 = vSrc0 + HD_;

#define STORE_VT(bufidx, va, vb) do {                                              \
        char* vtb = reinterpret_cast<char*>(&vt_lds[0][0]) + (bufidx) * 8192;      \
        _Pragma("unroll")                                                          \
        for (int j = 0; j < 8; ++j) {                                              \
            int byteoff = (dc * 8 + j) * 128 + ((4 * kp) ^ (j << 4));              \
            *reinterpret_cast<uint32_t*>(vtb + byteoff) = pkraw((va)[j], (vb)[j]); \
        }                                                                          \
    } while (0)

    bf16x8 v0 = *reinterpret_cast<const bf16x8*>(vSrc0);
    bf16x8 v1 = *reinterpret_cast<const bf16x8*>(vSrc1);
    gll16(kSrcA, &k_lds[0][w * 512]);
    gll16(kSrcB, &k_lds[0][2048 + w * 512]);
    STORE_VT(0, v0, v1);
    __syncthreads();

    for (int it = 0; it < NT_; ++it) {
        const int cur = it & 1, nxt = cur ^ 1;
        const bool more = (it + 1 < NT_);

        if (more) {
            size_t adv = (size_t)(it + 1) * 64 * HD_;
            v0 = *reinterpret_cast<const bf16x8*>(vSrc0 + adv);
            v1 = *reinterpret_cast<const bf16x8*>(vSrc1 + adv);
            gll16(kSrcA + adv, &k_lds[nxt][w * 512]);
            gll16(kSrcB + adv, &k_lds[nxt][2048 + w * 512]);
        }

        const char* kbase  = reinterpret_cast<const char*>(&k_lds[0][0]) + cur * 8192;
        const char* vtbase = reinterpret_cast<const char*>(&vt_lds[0][0]) + cur * 8192;
        float psum0 = 0.f, psum1 = 0.f;

#pragma unroll
        for (int s = 0; s < 2; ++s) {
            f32x16 st0 = {}, st1 = {};
            const int row = s * 32 + l31;
#pragma unroll
            for (int t = 0; t < 4; ++t) {
                int cc = (2 * t + h5) ^ (row & 7);
                bf16x8 kf = *reinterpret_cast<const bf16x8*>(kbase + row * 128 + cc * 16);
                st0 = __builtin_amdgcn_mfma_f32_32x32x16_bf16(kf, qf[0][t], st0, 0, 0, 0);
                st1 = __builtin_amdgcn_mfma_f32_32x32x16_bf16(kf, qf[1][t], st1, 0, 0, 0);
            }

#pragma unroll
            for (int i = 0; i < 16; ++i) st0[i] = EXP2(st0[i]);
#pragma unroll
            for (int i = 0; i < 16; ++i) st1[i] = EXP2(st1[i]);

            float t8[8], u8[8];
#pragma unroll
            for (int i = 0; i < 8; ++i) { t8[i] = st0[i] + st0[i + 8]; u8[i] = st1[i] + st1[i + 8]; }
#pragma unroll
            for (int i = 0; i < 4; ++i) { t8[i] = t8[i] + t8[i + 4];   u8[i] = u8[i] + u8[i + 4]; }
            psum0 += (t8[0] + t8[1]) + (t8[2] + t8[3]);
            psum1 += (u8[0] + u8[1]) + (u8[2] + u8[3]);

            uint32_t pk0[4][2], pk1[4][2];
#pragma unroll
            for (int g = 0; g < 4; ++g) {
                pk0[g][0] = pkbf(st0[4 * g + 0], st0[4 * g + 1]);
                pk0[g][1] = pkbf(st0[4 * g + 2], st0[4 * g + 3]);
                pk1[g][0] = pkbf(st1[4 * g + 0], st1[4 * g + 1]);
                pk1[g][1] = pkbf(st1[4 * g + 2], st1[4 * g + 3]);
            }
#pragma unroll
            for (int tt = 0; tt < 2; ++tt) {
                const int t = 2 * s + tt;
                uint32_t a0 = pk0[2 * tt][0], b0 = pk0[2 * tt + 1][0];
                uint32_t a1 = pk0[2 * tt][1], b1 = pk0[2 * tt + 1][1];
                uint32_t c0 = pk1[2 * tt][0], d0 = pk1[2 * tt + 1][0];
                uint32_t c1 = pk1[2 * tt][1], d1 = pk1[2 * tt + 1][1];
                asm volatile("v_permlane32_swap_b32 %0, %1" : "+v"(a0), "+v"(b0));
                asm volatile("v_permlane32_swap_b32 %0, %1" : "+v"(a1), "+v"(b1));
                asm volatile("v_permlane32_swap_b32 %0, %1" : "+v"(c0), "+v"(d0));
                asm volatile("v_permlane32_swap_b32 %0, %1" : "+v"(c1), "+v"(d1));
                union { uint32_t u[4]; bf16x8 v; } U0, U1;
                U0.u[0] = a0; U0.u[1] = a1; U0.u[2] = b0; U0.u[3] = b1;
                U1.u[0] = c0; U1.u[1] = c1; U1.u[2] = d0; U1.u[3] = d1;
#pragma unroll
                for (int n = 0; n < 2; ++n) {
                    int vrow = n * 32 + l31;
                    int cc   = (2 * t + h5) ^ (vrow & 7);
                    bf16x8 vf = *reinterpret_cast<const bf16x8*>(vtbase + vrow * 128 + cc * 16);
                    oT[0][n] = __builtin_amdgcn_mfma_f32_32x32x16_bf16(vf, U0.v, oT[0][n], 0, 0, 0);
                    oT[1][n] = __builtin_amdgcn_mfma_f32_32x32x16_bf16(vf, U1.v, oT[1][n], 0, 0, 0);
                }
            }

            if (s == 0 && more) STORE_VT(nxt, v0, v1);
        }

        psum0 += __shfl_xor(psum0, 32);
        psum1 += __shfl_xor(psum1, 32);
        l0 += psum0;
        l1 += psum1;

        __syncthreads();
    }

    const int b = bh >> 4, hh = bh & 15;
#pragma unroll
    for (int h = 0; h < 2; ++h) {
        float inv = 1.0f / (h ? l1 : l0);
        int q = q0 + h * 32 + l31;
#pragma unroll
        for (int n = 0; n < 2; ++n)
#pragma unroll
            for (int g = 0; g < 4; ++g) {
                int d = n * 32 + 8 * g + 4 * h5;
                bf16x4 o4;
#pragma unroll
                for (int r = 0; r < 4; ++r) o4[r] = (bf16)(oT[h][n][4 * g + r] * inv);
                *reinterpret_cast<bf16x4*>(Ob + ((size_t)(b * N_ + q)) * C_ + hh * 64 + d) = o4;
            }
    }
#undef STORE_VT
}

extern "C" void kernel_launch(void* const* d_in, const int* in_sizes, int n_in,
                              void* d_out, int out_size, void* d_ws, size_t ws_size,
                              hipStream_t stream) {
    const float* x     = (const float*)d_in[0];
    const float* wqkv  = (const float*)d_in[1];
    const float* wproj = (const float*)d_in[2];
    const float* bproj = (const float*)d_in[3];
    const float* fcos  = (const float*)d_in[4];
    const float* fsin  = (const float*)d_in[5];
    float* out = (float*)d_out;

    bf16* x_bf     = (bf16*)d_ws;
    bf16* wqkv_bf  = x_bf    + (size_t)M_ * C_;
    bf16* wproj_bf = wqkv_bf + (size_t)K3_ * C_;
    bf16* qbuf     = wproj_bf + (size_t)C_ * C_;
    bf16* kbuf     = qbuf  + (size_t)M_ * C_;
    bf16* vbuf     = kbuf  + (size_t)M_ * C_;
    bf16* abuf     = vbuf  + (size_t)M_ * C_;

    castk3<<<2048, 256, 0, stream>>>(x,     x_bf,     M_ * C_ / 4,
                                     wqkv,  wqkv_bf,  K3_ * C_ / 4,
                                     wproj, wproj_bf, C_ * C_ / 4);

    gemm_bt<0><<<64 * 24, 256, 0, stream>>>(x_bf, wqkv_bf, K3_, C_,
                                            qbuf, kbuf, vbuf, fcos, fsin, nullptr, nullptr);
    attn_kernel<<<64 * 8, 256, 0, stream>>>(qbuf, kbuf, vbuf, abuf);
    gemm_bt<1><<<64 * 8, 256, 0, stream>>>(abuf, wproj_bf, C_, C_,
                                           nullptr, nullptr, nullptr, nullptr, nullptr, bproj, out);
}